// Round 7
// baseline (50.629 us; speedup 1.0000x reference)
//
#include <hip/hip_runtime.h>

#define N 4096
#define MASK 4095

// 32-lane butterfly sum (within each 32-lane half of a wave64).
__device__ __forceinline__ float red32(float v) {
    v += __shfl_xor(v, 1, 64);
    v += __shfl_xor(v, 2, 64);
    v += __shfl_xor(v, 4, 64);
    v += __shfl_xor(v, 8, 64);
    v += __shfl_xor(v, 16, 64);
    return v;
}

// Merge-tree reduction used by K3 (4 independent 64-lane sums, 7 shuffles).
// Result mapping: lane-group sg = lane>>4: sg0->g0, sg1->g2, sg2->g1, sg3->g3.
__device__ __forceinline__ float fold(float u, float v, int m) {
    const bool hi = (threadIdx.x & m) != 0;
    const float t = hi ? u : v;
    const float s = __shfl_xor(t, m, 64);
    return (hi ? v : u) + s;
}

__device__ __forceinline__ float greduce4(float g0, float g1, float g2, float g3) {
    float c1 = fold(g0, g1, 32);
    float c2 = fold(g2, g3, 32);
    float e  = fold(c1, c2, 16);
    e += __shfl_xor(e, 8, 64);
    e += __shfl_xor(e, 4, 64);
    e += __shfl_xor(e, 2, 64);
    e += __shfl_xor(e, 1, 64);
    return e;
}

// ---------------------------------------------------------------------------
// K1: fused single pass over km1 and km2.
//   1024 blocks x 256 threads: rc = b>>2 owns 16 rows, cs = b&3 owns a
//   1024-col stripe. Thread t owns cols cs*1024 + 4t..4t+3 (one float4 per
//   row per matrix). Hot loop = pure loads + FMAs; per-row dot partials in
//   registers dpa[16]/dpb[16]; cross-lane ops ONLY in the epilogue.
//   amdgpu_waves_per_eu(4,4): rounds 5/6 showed __launch_bounds__ min-waves
//   does NOT stop the allocator from targeting 8 waves/EU (64-VGPR cap) and
//   spilling ~31 MB; capping max waves at 4 gives a 128-VGPR budget for the
//   ~110-register working set -> no spills.
// ---------------------------------------------------------------------------
__global__ __launch_bounds__(256)
__attribute__((amdgpu_waves_per_eu(4, 4)))
void k1_fused(
    const float* __restrict__ key,
    const float* __restrict__ km1, const float* __restrict__ km2,
    const float* __restrict__ o1, const float* __restrict__ o2,
    float* __restrict__ tpart1, float* __restrict__ tpart2,
    float* __restrict__ dpart1, float* __restrict__ dpart2)
{
    __shared__ float skey[4096 + 128];
    __shared__ float sdp[32][8];         // [m*16+r][half-wave]
    const int t = threadIdx.x;
    const int b = blockIdx.x;
    const int rc = b >> 2;
    const int cs = b & 3;
    const int j0 = rc * 16;
    const int c0 = cs * 1024;

    #pragma unroll
    for (int q = 0; q < 4; ++q) {
        const float4 kv = ((const float4*)key)[q * 256 + t];
        const int idx = (q * 256 + t) * 4;
        skey[(idx + 0) + ((idx + 0) >> 5)] = kv.x;
        skey[(idx + 1) + ((idx + 1) >> 5)] = kv.y;
        skey[(idx + 2) + ((idx + 2) >> 5)] = kv.z;
        skey[(idx + 3) + ((idx + 3) >> 5)] = kv.w;
    }
    __syncthreads();

    // key window: w[i] = key[(c0 + 4t - j0 - 15 + i) & 4095], i = 0..18
    // row j0+r, col c0+4t+cx  ->  w[cx + 15 - r]
    float w[19];
    #pragma unroll
    for (int i = 0; i < 19; ++i) {
        const int idx = (c0 + 4 * t - j0 - 15 + i) & MASK;
        w[i] = skey[idx + (idx >> 5)];
    }

    const float4* q1 = (const float4*)km1 + (size_t)j0 * 1024 + cs * 256 + t;
    const float4* q2 = (const float4*)km2 + (size_t)j0 * 1024 + cs * 256 + t;

    float dpa[16], dpb[16];
    float tp1[4] = {0.f, 0.f, 0.f, 0.f};
    float tp2[4] = {0.f, 0.f, 0.f, 0.f};

    #pragma unroll
    for (int rb = 0; rb < 4; ++rb) {
        float4 A[4], B[4];
        #pragma unroll
        for (int i = 0; i < 4; ++i) A[i] = q1[(size_t)(rb * 4 + i) * 1024];
        #pragma unroll
        for (int i = 0; i < 4; ++i) B[i] = q2[(size_t)(rb * 4 + i) * 1024];
        #pragma unroll
        for (int rr = 0; rr < 4; ++rr) {
            const int r = rb * 4 + rr;
            const float4 a = A[rr];
            const float4 v = B[rr];
            const float oa = o1[j0 + r], ob = o2[j0 + r];
            tp1[0] += oa * a.x; tp1[1] += oa * a.y; tp1[2] += oa * a.z; tp1[3] += oa * a.w;
            tp2[0] += ob * v.x; tp2[1] += ob * v.y; tp2[2] += ob * v.z; tp2[3] += ob * v.w;
            dpa[r] = w[15 - r] * a.x + w[16 - r] * a.y + w[17 - r] * a.z + w[18 - r] * a.w;
            dpb[r] = w[15 - r] * v.x + w[16 - r] * v.y + w[17 - r] * v.z + w[18 - r] * v.w;
        }
    }

    // t-partials out first (frees the load path).
    ((float4*)(tpart1 + (size_t)rc * N + c0))[t] = make_float4(tp1[0], tp1[1], tp1[2], tp1[3]);
    ((float4*)(tpart2 + (size_t)rc * N + c0))[t] = make_float4(tp2[0], tp2[1], tp2[2], tp2[3]);

    // Epilogue stage 1: half-wave butterflies, leaders write sdp[g][hw].
    const int hw = t >> 5;               // half-wave index 0..7
    #pragma unroll
    for (int m = 0; m < 2; ++m) {
        #pragma unroll
        for (int r = 0; r < 16; ++r) {
            const float v = red32(m ? dpb[r] : dpa[r]);
            if ((t & 31) == 0) sdp[m * 16 + r][hw] = v;
        }
    }
    __syncthreads();

    // Epilogue stage 2: 32 groups x 8 partials -> per-stripe d partial.
    {
        const int g = t >> 3;            // m*16 + r
        const int s = t & 7;
        float v = sdp[g][s];
        v += __shfl_xor(v, 1, 64);
        v += __shfl_xor(v, 2, 64);
        v += __shfl_xor(v, 4, 64);
        if (s == 0) {
            const int m = g >> 4, r = g & 15;
            (m ? dpart2 : dpart1)[(size_t)(j0 + r) * 4 + cs] = v;
        }
    }
}

// ---------------------------------------------------------------------------
// K2: reduce partials. grid = 272 x 256.
//   blocks [0,256):    t-reduce over 256 slices (32 cols per block).
//   blocks [256,272):  d-reduce: one float4 (4 stripes) per row per thread.
// ---------------------------------------------------------------------------
__global__ __launch_bounds__(256) void k2_reduce(
    const float* __restrict__ tpart1, const float* __restrict__ tpart2,
    const float* __restrict__ dpart1, const float* __restrict__ dpart2,
    float* __restrict__ t1, float* __restrict__ t2,
    float* __restrict__ d1, float* __restrict__ d2)
{
    __shared__ float sdata[256];
    const int b = blockIdx.x;
    const int t = threadIdx.x;

    if (b < 256) {
        const float* src = (b < 128) ? tpart1 : tpart2;
        float* dst       = (b < 128) ? t1 : t2;
        const int colbase = (b & 127) * 32;
        const int col = t & 31;
        const int sg = t >> 5;
        float a0 = 0.f, a1 = 0.f, a2 = 0.f, a3 = 0.f;
        #pragma unroll 4
        for (int k = 0; k < 32; k += 4) {
            a0 += src[(size_t)(sg + 8 * (k + 0)) * N + colbase + col];
            a1 += src[(size_t)(sg + 8 * (k + 1)) * N + colbase + col];
            a2 += src[(size_t)(sg + 8 * (k + 2)) * N + colbase + col];
            a3 += src[(size_t)(sg + 8 * (k + 3)) * N + colbase + col];
        }
        sdata[t] = (a0 + a1) + (a2 + a3);
        __syncthreads();
        if (t < 32) {
            float s = 0.f;
            #pragma unroll
            for (int i = 0; i < 8; ++i) s += sdata[i * 32 + t];
            dst[colbase + t] = s;
        }
    } else {
        const int row = (b - 256) * 256 + t;
        const float4 v1 = ((const float4*)dpart1)[row];
        const float4 v2 = ((const float4*)dpart2)[row];
        d1[row] = (v1.x + v1.y) + (v1.z + v1.w);
        d2[row] = (v2.x + v2.y) + (v2.z + v2.w);
    }
}

// ---------------------------------------------------------------------------
// K3: three circulant matvecs + final combine. 1024 blocks x 4 rows each.
// ---------------------------------------------------------------------------
__global__ __launch_bounds__(256) void k3_final(
    const float* __restrict__ key, const float* __restrict__ x,
    const float* __restrict__ t1, const float* __restrict__ t2,
    const float* __restrict__ d1, const float* __restrict__ d2,
    const float* __restrict__ o1, const float* __restrict__ o2,
    float* __restrict__ out)
{
    __shared__ float skey[4096 + 128];
    __shared__ float sred[48];                 // [wave][v][row]
    const int t = threadIdx.x;
    const int j0 = blockIdx.x * 4;

    #pragma unroll
    for (int q = 0; q < 16; ++q) {
        const int idx = q * 256 + t;
        skey[idx + (idx >> 5)] = key[idx];
    }
    __syncthreads();

    float acc[4][3];
    #pragma unroll
    for (int r = 0; r < 4; ++r)
        #pragma unroll
        for (int v = 0; v < 3; ++v) acc[r][v] = 0.f;

    #pragma unroll
    for (int q = 0; q < 4; ++q) {
        const int k0 = q * 1024 + 4 * t;
        const float4 xv = *(const float4*)(x + k0);
        const float4 u1 = *(const float4*)(t1 + k0);
        const float4 u2 = *(const float4*)(t2 + k0);
        float kw[7];                           // (k0 + c - j0 - r), c:0..3, r:0..3
        #pragma unroll
        for (int i = 0; i < 7; ++i) {
            const int widx = (k0 - j0 - 3 + i) & MASK;
            kw[i] = skey[widx + (widx >> 5)];
        }
        #pragma unroll
        for (int r = 0; r < 4; ++r) {
            const float kv0 = kw[3 - r], kv1 = kw[4 - r], kv2 = kw[5 - r], kv3 = kw[6 - r];
            acc[r][0] += kv0 * xv.x + kv1 * xv.y + kv2 * xv.z + kv3 * xv.w;
            acc[r][1] += kv0 * u1.x + kv1 * u1.y + kv2 * u1.z + kv3 * u1.w;
            acc[r][2] += kv0 * u2.x + kv1 * u2.y + kv2 * u2.z + kv3 * u2.w;
        }
    }

    float rv[3];
    #pragma unroll
    for (int v = 0; v < 3; ++v)
        rv[v] = greduce4(acc[0][v], acc[1][v], acc[2][v], acc[3][v]);

    const int lane = t & 63, wave = t >> 6, sg = lane >> 4;
    const int off = (0x3120 >> (sg * 4)) & 0xF;  // which row this lane holds
    if ((lane & 15) == 0) {
        #pragma unroll
        for (int v = 0; v < 3; ++v) sred[wave * 12 + v * 4 + off] = rv[v];
    }
    __syncthreads();

    if (t < 4) {
        const int j = j0 + t;
        float vb = 0.f, v1 = 0.f, v2 = 0.f;
        #pragma unroll
        for (int wv = 0; wv < 4; ++wv) {
            vb += sred[wv * 12 + 0 + t];
            v1 += sred[wv * 12 + 4 + t];
            v2 += sred[wv * 12 + 8 + t];
        }
        const float dd1 = d1[j], dd2 = d2[j];
        const float r2 = v1 - dd1 * o1[j];
        const float r4 = v2 - dd2 * o2[j];
        out[j] = (vb - r2 - r4) / dd1;
        if (j == N - 1) out[N] = dd2;          // redun3 = d2[last row]
    }
}

extern "C" void kernel_launch(void* const* d_in, const int* in_sizes, int n_in,
                              void* d_out, int out_size, void* d_ws, size_t ws_size,
                              hipStream_t stream) {
    const float* key = (const float*)d_in[0];
    const float* x   = (const float*)d_in[1];
    const float* km1 = (const float*)d_in[2];
    const float* o1  = (const float*)d_in[3];
    const float* km2 = (const float*)d_in[4];
    const float* o2  = (const float*)d_in[5];
    float* out = (float*)d_out;

    float* ws = (float*)d_ws;
    float* tpart1 = ws;                                  // 256*4096
    float* tpart2 = tpart1 + (size_t)256 * N;            // 256*4096
    float* dpart1 = tpart2 + (size_t)256 * N;            // 4096*4
    float* dpart2 = dpart1 + (size_t)N * 4;              // 4096*4
    float* t1     = dpart2 + (size_t)N * 4;              // 4096
    float* t2     = t1 + N;
    float* d1     = t2 + N;
    float* d2     = d1 + N;

    hipLaunchKernelGGL(k1_fused, dim3(1024), dim3(256), 0, stream,
                       key, km1, km2, o1, o2, tpart1, tpart2, dpart1, dpart2);
    hipLaunchKernelGGL(k2_reduce, dim3(272), dim3(256), 0, stream,
                       tpart1, tpart2, dpart1, dpart2, t1, t2, d1, d2);
    hipLaunchKernelGGL(k3_final, dim3(1024), dim3(256), 0, stream,
                       key, x, t1, t2, d1, d2, o1, o2, out);
}

// Round 8
// 38.313 us; speedup vs baseline: 1.3214x; 1.3214x over previous
//
#include <hip/hip_runtime.h>

#define N 4096
#define MASK 4095

// 32-lane butterfly sum (within each 32-lane half of a wave64).
__device__ __forceinline__ float red32(float v) {
    v += __shfl_xor(v, 1, 64);
    v += __shfl_xor(v, 2, 64);
    v += __shfl_xor(v, 4, 64);
    v += __shfl_xor(v, 8, 64);
    v += __shfl_xor(v, 16, 64);
    return v;
}

// Merge-tree reduction used by K3 (4 independent 64-lane sums, 7 shuffles).
// Result mapping: lane-group sg = lane>>4: sg0->g0, sg1->g2, sg2->g1, sg3->g3.
__device__ __forceinline__ float fold(float u, float v, int m) {
    const bool hi = (threadIdx.x & m) != 0;
    const float t = hi ? u : v;
    const float s = __shfl_xor(t, m, 64);
    return (hi ? v : u) + s;
}

__device__ __forceinline__ float greduce4(float g0, float g1, float g2, float g3) {
    float c1 = fold(g0, g1, 32);
    float c2 = fold(g2, g3, 32);
    float e  = fold(c1, c2, 16);
    e += __shfl_xor(e, 8, 64);
    e += __shfl_xor(e, 4, 64);
    e += __shfl_xor(e, 2, 64);
    e += __shfl_xor(e, 1, 64);
    return e;
}

// ---------------------------------------------------------------------------
// K1: single pass over one matrix per block, sized to fit the 64-VGPR
//   budget the allocator insists on (rounds 4-7: any >64-reg working set
//   got scratch-spilled, ~35 MB of spill traffic).
//   grid 4096 x 256: mat = b>>11 (km1/km2), rc = (b&2047)>>2 owns 8 rows,
//   cs = b&3 owns a 1024-col stripe. Thread t owns cols c0+4t..4t+3.
//   State: dpa[8] + w[11] + float4 A[4] + tp[4]  (~53 regs, no spills).
//   Key window read directly from global (L1-resident 16 KB array) -- no
//   LDS staging; LDS is just the 256 B sdp reduction buffer.
// ---------------------------------------------------------------------------
__global__ __launch_bounds__(256) void k1_fused(
    const float* __restrict__ key,
    const float* __restrict__ km1, const float* __restrict__ km2,
    const float* __restrict__ o1, const float* __restrict__ o2,
    float* __restrict__ tpart1, float* __restrict__ tpart2,
    float* __restrict__ dpart1, float* __restrict__ dpart2)
{
    __shared__ float sdp[8][8];          // [row][half-wave]
    const int t = threadIdx.x;
    const int b = blockIdx.x;
    const int mat = b >> 11;
    const int bb = b & 2047;
    const int rc = bb >> 2;
    const int cs = bb & 3;
    const int j0 = rc * 8;
    const int c0 = cs * 1024;

    const float* __restrict__ km = mat ? km2 : km1;
    const float* __restrict__ o  = mat ? o2  : o1;
    float* __restrict__ tp_out   = mat ? tpart2 : tpart1;
    float* __restrict__ dp_out   = mat ? dpart2 : dpart1;

    // key window: w[i] = key[(c0 + 4t - j0 - 7 + i) & 4095], i = 0..10
    // row j0+r, col c0+4t+cx  ->  w[cx + 7 - r]
    float w[11];
    #pragma unroll
    for (int i = 0; i < 11; ++i)
        w[i] = key[(c0 + 4 * t - j0 - 7 + i) & MASK];

    const float4* q = (const float4*)km + (size_t)j0 * 1024 + cs * 256 + t;

    float dpa[8];
    float tp[4] = {0.f, 0.f, 0.f, 0.f};

    #pragma unroll
    for (int rb = 0; rb < 2; ++rb) {
        float4 A[4];
        #pragma unroll
        for (int i = 0; i < 4; ++i) A[i] = q[(size_t)(rb * 4 + i) * 1024];
        #pragma unroll
        for (int rr = 0; rr < 4; ++rr) {
            const int r = rb * 4 + rr;
            const float4 a = A[rr];
            const float oa = o[j0 + r];
            tp[0] += oa * a.x; tp[1] += oa * a.y; tp[2] += oa * a.z; tp[3] += oa * a.w;
            dpa[r] = w[7 - r] * a.x + w[8 - r] * a.y + w[9 - r] * a.z + w[10 - r] * a.w;
        }
    }

    // t-partials out first (frees the load path).
    ((float4*)(tp_out + (size_t)rc * N + c0))[t] = make_float4(tp[0], tp[1], tp[2], tp[3]);

    // Epilogue stage 1: half-wave butterflies, leaders write sdp[r][hw].
    const int hw = t >> 5;               // half-wave index 0..7
    #pragma unroll
    for (int r = 0; r < 8; ++r) {
        const float v = red32(dpa[r]);
        if ((t & 31) == 0) sdp[r][hw] = v;
    }
    __syncthreads();

    // Epilogue stage 2: 8 rows x 8 partials -> per-stripe d partial.
    if (t < 64) {
        const int g = t >> 3;            // row 0..7
        const int s = t & 7;
        float v = sdp[g][s];
        v += __shfl_xor(v, 1, 64);
        v += __shfl_xor(v, 2, 64);
        v += __shfl_xor(v, 4, 64);
        if (s == 0) dp_out[(size_t)(j0 + g) * 4 + cs] = v;
    }
}

// ---------------------------------------------------------------------------
// K2: reduce partials. grid = 272 x 256.
//   blocks [0,256):    t-reduce over 512 slices (32 cols per block).
//   blocks [256,272):  d-reduce: one float4 (4 stripes) per row per thread.
// ---------------------------------------------------------------------------
__global__ __launch_bounds__(256) void k2_reduce(
    const float* __restrict__ tpart1, const float* __restrict__ tpart2,
    const float* __restrict__ dpart1, const float* __restrict__ dpart2,
    float* __restrict__ t1, float* __restrict__ t2,
    float* __restrict__ d1, float* __restrict__ d2)
{
    __shared__ float sdata[256];
    const int b = blockIdx.x;
    const int t = threadIdx.x;

    if (b < 256) {
        const float* src = (b < 128) ? tpart1 : tpart2;
        float* dst       = (b < 128) ? t1 : t2;
        const int colbase = (b & 127) * 32;
        const int col = t & 31;
        const int sg = t >> 5;
        float a0 = 0.f, a1 = 0.f, a2 = 0.f, a3 = 0.f;
        #pragma unroll 4
        for (int k = 0; k < 64; k += 4) {
            a0 += src[(size_t)(sg + 8 * (k + 0)) * N + colbase + col];
            a1 += src[(size_t)(sg + 8 * (k + 1)) * N + colbase + col];
            a2 += src[(size_t)(sg + 8 * (k + 2)) * N + colbase + col];
            a3 += src[(size_t)(sg + 8 * (k + 3)) * N + colbase + col];
        }
        sdata[t] = (a0 + a1) + (a2 + a3);
        __syncthreads();
        if (t < 32) {
            float s = 0.f;
            #pragma unroll
            for (int i = 0; i < 8; ++i) s += sdata[i * 32 + t];
            dst[colbase + t] = s;
        }
    } else {
        const int row = (b - 256) * 256 + t;
        const float4 v1 = ((const float4*)dpart1)[row];
        const float4 v2 = ((const float4*)dpart2)[row];
        d1[row] = (v1.x + v1.y) + (v1.z + v1.w);
        d2[row] = (v2.x + v2.y) + (v2.z + v2.w);
    }
}

// ---------------------------------------------------------------------------
// K3: three circulant matvecs + final combine. 1024 blocks x 4 rows each.
// ---------------------------------------------------------------------------
__global__ __launch_bounds__(256) void k3_final(
    const float* __restrict__ key, const float* __restrict__ x,
    const float* __restrict__ t1, const float* __restrict__ t2,
    const float* __restrict__ d1, const float* __restrict__ d2,
    const float* __restrict__ o1, const float* __restrict__ o2,
    float* __restrict__ out)
{
    __shared__ float skey[4096 + 128];
    __shared__ float sred[48];                 // [wave][v][row]
    const int t = threadIdx.x;
    const int j0 = blockIdx.x * 4;

    #pragma unroll
    for (int q = 0; q < 16; ++q) {
        const int idx = q * 256 + t;
        skey[idx + (idx >> 5)] = key[idx];
    }
    __syncthreads();

    float acc[4][3];
    #pragma unroll
    for (int r = 0; r < 4; ++r)
        #pragma unroll
        for (int v = 0; v < 3; ++v) acc[r][v] = 0.f;

    #pragma unroll
    for (int q = 0; q < 4; ++q) {
        const int k0 = q * 1024 + 4 * t;
        const float4 xv = *(const float4*)(x + k0);
        const float4 u1 = *(const float4*)(t1 + k0);
        const float4 u2 = *(const float4*)(t2 + k0);
        float kw[7];                           // (k0 + c - j0 - r), c:0..3, r:0..3
        #pragma unroll
        for (int i = 0; i < 7; ++i) {
            const int widx = (k0 - j0 - 3 + i) & MASK;
            kw[i] = skey[widx + (widx >> 5)];
        }
        #pragma unroll
        for (int r = 0; r < 4; ++r) {
            const float kv0 = kw[3 - r], kv1 = kw[4 - r], kv2 = kw[5 - r], kv3 = kw[6 - r];
            acc[r][0] += kv0 * xv.x + kv1 * xv.y + kv2 * xv.z + kv3 * xv.w;
            acc[r][1] += kv0 * u1.x + kv1 * u1.y + kv2 * u1.z + kv3 * u1.w;
            acc[r][2] += kv0 * u2.x + kv1 * u2.y + kv2 * u2.z + kv3 * u2.w;
        }
    }

    float rv[3];
    #pragma unroll
    for (int v = 0; v < 3; ++v)
        rv[v] = greduce4(acc[0][v], acc[1][v], acc[2][v], acc[3][v]);

    const int lane = t & 63, wave = t >> 6, sg = lane >> 4;
    const int off = (0x3120 >> (sg * 4)) & 0xF;  // which row this lane holds
    if ((lane & 15) == 0) {
        #pragma unroll
        for (int v = 0; v < 3; ++v) sred[wave * 12 + v * 4 + off] = rv[v];
    }
    __syncthreads();

    if (t < 4) {
        const int j = j0 + t;
        float vb = 0.f, v1 = 0.f, v2 = 0.f;
        #pragma unroll
        for (int wv = 0; wv < 4; ++wv) {
            vb += sred[wv * 12 + 0 + t];
            v1 += sred[wv * 12 + 4 + t];
            v2 += sred[wv * 12 + 8 + t];
        }
        const float dd1 = d1[j], dd2 = d2[j];
        const float r2 = v1 - dd1 * o1[j];
        const float r4 = v2 - dd2 * o2[j];
        out[j] = (vb - r2 - r4) / dd1;
        if (j == N - 1) out[N] = dd2;          // redun3 = d2[last row]
    }
}

extern "C" void kernel_launch(void* const* d_in, const int* in_sizes, int n_in,
                              void* d_out, int out_size, void* d_ws, size_t ws_size,
                              hipStream_t stream) {
    const float* key = (const float*)d_in[0];
    const float* x   = (const float*)d_in[1];
    const float* km1 = (const float*)d_in[2];
    const float* o1  = (const float*)d_in[3];
    const float* km2 = (const float*)d_in[4];
    const float* o2  = (const float*)d_in[5];
    float* out = (float*)d_out;

    float* ws = (float*)d_ws;
    float* tpart1 = ws;                                  // 512*4096
    float* tpart2 = tpart1 + (size_t)512 * N;            // 512*4096
    float* dpart1 = tpart2 + (size_t)512 * N;            // 4096*4
    float* dpart2 = dpart1 + (size_t)N * 4;              // 4096*4
    float* t1     = dpart2 + (size_t)N * 4;              // 4096
    float* t2     = t1 + N;
    float* d1     = t2 + N;
    float* d2     = d1 + N;

    hipLaunchKernelGGL(k1_fused, dim3(4096), dim3(256), 0, stream,
                       key, km1, km2, o1, o2, tpart1, tpart2, dpart1, dpart2);
    hipLaunchKernelGGL(k2_reduce, dim3(272), dim3(256), 0, stream,
                       tpart1, tpart2, dpart1, dpart2, t1, t2, d1, d2);
    hipLaunchKernelGGL(k3_final, dim3(1024), dim3(256), 0, stream,
                       key, x, t1, t2, d1, d2, o1, o2, out);
}

// Round 9
// 37.474 us; speedup vs baseline: 1.3510x; 1.0224x over previous
//
#include <hip/hip_runtime.h>

#define N 4096
#define MASK 4095

// 32-lane butterfly sum (within each 32-lane half of a wave64).
__device__ __forceinline__ float red32(float v) {
    v += __shfl_xor(v, 1, 64);
    v += __shfl_xor(v, 2, 64);
    v += __shfl_xor(v, 4, 64);
    v += __shfl_xor(v, 8, 64);
    v += __shfl_xor(v, 16, 64);
    return v;
}

// Merge-tree reduction used by K3 (4 independent 64-lane sums, 7 shuffles).
// Result mapping: lane-group sg = lane>>4: sg0->g0, sg1->g2, sg2->g1, sg3->g3.
__device__ __forceinline__ float fold(float u, float v, int m) {
    const bool hi = (threadIdx.x & m) != 0;
    const float t = hi ? u : v;
    const float s = __shfl_xor(t, m, 64);
    return (hi ? v : u) + s;
}

__device__ __forceinline__ float greduce4(float g0, float g1, float g2, float g3) {
    float c1 = fold(g0, g1, 32);
    float c2 = fold(g2, g3, 32);
    float e  = fold(c1, c2, 16);
    e += __shfl_xor(e, 8, 64);
    e += __shfl_xor(e, 4, 64);
    e += __shfl_xor(e, 2, 64);
    e += __shfl_xor(e, 1, 64);
    return e;
}

// ---------------------------------------------------------------------------
// K1: single pass, one matrix per block, 16 rows x 2048 cols per block
//   (64 KB retired/block -- 2x round 8 -- amortizing epilogue + key reads).
//   grid 1024 x 256: mat = b>>9; sub = b&511; rc = sub>>1 (16-row chunk),
//   cs = sub&1 (2048-col stripe). Thread t owns cols c0+8t..8t+7.
//   Key staged once in padded LDS (stride-8 reads + (idx>>5) pad = 2
//   lanes/bank = conflict-free); 15-reg window per 8-row half.
//   Working set ~60 VGPR -- fits the 64-VGPR budget the allocator enforces
//   (rounds 4-7 lesson). Per-row dot partials dpa[8] in registers; red32
//   leaders write dpart[row][16] directly (no 2nd LDS stage, no barrier).
// ---------------------------------------------------------------------------
__global__ __launch_bounds__(256) void k1_fused(
    const float* __restrict__ key,
    const float* __restrict__ km1, const float* __restrict__ km2,
    const float* __restrict__ o1, const float* __restrict__ o2,
    float* __restrict__ tpart1, float* __restrict__ tpart2,
    float* __restrict__ dpart1, float* __restrict__ dpart2)
{
    __shared__ float skey[4096 + 128];
    const int t = threadIdx.x;
    const int b = blockIdx.x;
    const int mat = b >> 9;
    const int sub = b & 511;
    const int rc = sub >> 1;
    const int cs = sub & 1;
    const int j0 = rc * 16;
    const int c0 = cs * 2048;

    const float* __restrict__ km = mat ? km2 : km1;
    const float* __restrict__ o  = mat ? o2  : o1;
    float* __restrict__ tp_out   = mat ? tpart2 : tpart1;
    float* __restrict__ dp_out   = mat ? dpart2 : dpart1;

    #pragma unroll
    for (int q = 0; q < 4; ++q) {
        const float4 kv = ((const float4*)key)[q * 256 + t];
        const int idx = (q * 256 + t) * 4;
        skey[(idx + 0) + ((idx + 0) >> 5)] = kv.x;
        skey[(idx + 1) + ((idx + 1) >> 5)] = kv.y;
        skey[(idx + 2) + ((idx + 2) >> 5)] = kv.z;
        skey[(idx + 3) + ((idx + 3) >> 5)] = kv.w;
    }
    __syncthreads();

    const int col0 = c0 + 8 * t;
    const float4* qp = (const float4*)km + (size_t)j0 * 1024 + (c0 >> 2) + 2 * t;
    const int hw = t >> 5;               // half-wave index 0..7

    float tp[8];
    #pragma unroll
    for (int i = 0; i < 8; ++i) tp[i] = 0.f;

    for (int h = 0; h < 2; ++h) {
        const int jbase = j0 + 8 * h;
        const float4* qh = qp + (size_t)h * 8 * 1024;

        // key window for this half: w[i] = key[(col0 - jbase - 7 + i) & 4095]
        // row jbase+r, col col0+cx  ->  w[cx + 7 - r]
        float w[15];
        #pragma unroll
        for (int i = 0; i < 15; ++i) {
            const int idx = (col0 - jbase - 7 + i) & MASK;
            w[i] = skey[idx + (idx >> 5)];
        }

        float dpa[8];
        #pragma unroll
        for (int rb = 0; rb < 4; ++rb) {
            const int r0 = 2 * rb, r1 = 2 * rb + 1;
            const float4 a0 = qh[(size_t)r0 * 1024];
            const float4 b0 = qh[(size_t)r0 * 1024 + 1];
            const float4 a1 = qh[(size_t)r1 * 1024];
            const float4 b1 = qh[(size_t)r1 * 1024 + 1];
            const float oa0 = o[jbase + r0];
            const float oa1 = o[jbase + r1];

            tp[0] += oa0 * a0.x; tp[1] += oa0 * a0.y; tp[2] += oa0 * a0.z; tp[3] += oa0 * a0.w;
            tp[4] += oa0 * b0.x; tp[5] += oa0 * b0.y; tp[6] += oa0 * b0.z; tp[7] += oa0 * b0.w;
            dpa[r0] = w[7 - r0] * a0.x + w[8 - r0] * a0.y + w[9 - r0] * a0.z + w[10 - r0] * a0.w
                    + w[11 - r0] * b0.x + w[12 - r0] * b0.y + w[13 - r0] * b0.z + w[14 - r0] * b0.w;

            tp[0] += oa1 * a1.x; tp[1] += oa1 * a1.y; tp[2] += oa1 * a1.z; tp[3] += oa1 * a1.w;
            tp[4] += oa1 * b1.x; tp[5] += oa1 * b1.y; tp[6] += oa1 * b1.z; tp[7] += oa1 * b1.w;
            dpa[r1] = w[7 - r1] * a1.x + w[8 - r1] * a1.y + w[9 - r1] * a1.z + w[10 - r1] * a1.w
                    + w[11 - r1] * b1.x + w[12 - r1] * b1.y + w[13 - r1] * b1.z + w[14 - r1] * b1.w;
        }

        // per-half reduction: half-wave butterflies, leaders write dpart.
        #pragma unroll
        for (int r = 0; r < 8; ++r) {
            const float v = red32(dpa[r]);
            if ((t & 31) == 0)
                dp_out[(size_t)(jbase + r) * 16 + cs * 8 + hw] = v;
        }
    }

    // t-partials: 8 cols/thread = two float4 stores.
    float4* tpo = (float4*)(tp_out + (size_t)rc * N + c0) + 2 * t;
    tpo[0] = make_float4(tp[0], tp[1], tp[2], tp[3]);
    tpo[1] = make_float4(tp[4], tp[5], tp[6], tp[7]);
}

// ---------------------------------------------------------------------------
// K2: reduce partials. grid = 272 x 256.
//   blocks [0,256):    t-reduce over 256 slices (32 cols per block).
//   blocks [256,272):  d-reduce: 16 partials per row per thread.
// ---------------------------------------------------------------------------
__global__ __launch_bounds__(256) void k2_reduce(
    const float* __restrict__ tpart1, const float* __restrict__ tpart2,
    const float* __restrict__ dpart1, const float* __restrict__ dpart2,
    float* __restrict__ t1, float* __restrict__ t2,
    float* __restrict__ d1, float* __restrict__ d2)
{
    __shared__ float sdata[256];
    const int b = blockIdx.x;
    const int t = threadIdx.x;

    if (b < 256) {
        const float* src = (b < 128) ? tpart1 : tpart2;
        float* dst       = (b < 128) ? t1 : t2;
        const int colbase = (b & 127) * 32;
        const int col = t & 31;
        const int sg = t >> 5;
        float a0 = 0.f, a1 = 0.f, a2 = 0.f, a3 = 0.f;
        #pragma unroll 4
        for (int k = 0; k < 32; k += 4) {
            a0 += src[(size_t)(sg + 8 * (k + 0)) * N + colbase + col];
            a1 += src[(size_t)(sg + 8 * (k + 1)) * N + colbase + col];
            a2 += src[(size_t)(sg + 8 * (k + 2)) * N + colbase + col];
            a3 += src[(size_t)(sg + 8 * (k + 3)) * N + colbase + col];
        }
        sdata[t] = (a0 + a1) + (a2 + a3);
        __syncthreads();
        if (t < 32) {
            float s = 0.f;
            #pragma unroll
            for (int i = 0; i < 8; ++i) s += sdata[i * 32 + t];
            dst[colbase + t] = s;
        }
    } else {
        const int row = (b - 256) * 256 + t;
        const float4* p1 = (const float4*)(dpart1 + (size_t)row * 16);
        const float4* p2 = (const float4*)(dpart2 + (size_t)row * 16);
        float s1 = 0.f, s2 = 0.f;
        #pragma unroll
        for (int i = 0; i < 4; ++i) {
            const float4 v1 = p1[i];
            const float4 v2 = p2[i];
            s1 += (v1.x + v1.y) + (v1.z + v1.w);
            s2 += (v2.x + v2.y) + (v2.z + v2.w);
        }
        d1[row] = s1;
        d2[row] = s2;
    }
}

// ---------------------------------------------------------------------------
// K3: three circulant matvecs + final combine. 1024 blocks x 4 rows each.
// ---------------------------------------------------------------------------
__global__ __launch_bounds__(256) void k3_final(
    const float* __restrict__ key, const float* __restrict__ x,
    const float* __restrict__ t1, const float* __restrict__ t2,
    const float* __restrict__ d1, const float* __restrict__ d2,
    const float* __restrict__ o1, const float* __restrict__ o2,
    float* __restrict__ out)
{
    __shared__ float skey[4096 + 128];
    __shared__ float sred[48];                 // [wave][v][row]
    const int t = threadIdx.x;
    const int j0 = blockIdx.x * 4;

    #pragma unroll
    for (int q = 0; q < 16; ++q) {
        const int idx = q * 256 + t;
        skey[idx + (idx >> 5)] = key[idx];
    }
    __syncthreads();

    float acc[4][3];
    #pragma unroll
    for (int r = 0; r < 4; ++r)
        #pragma unroll
        for (int v = 0; v < 3; ++v) acc[r][v] = 0.f;

    #pragma unroll
    for (int q = 0; q < 4; ++q) {
        const int k0 = q * 1024 + 4 * t;
        const float4 xv = *(const float4*)(x + k0);
        const float4 u1 = *(const float4*)(t1 + k0);
        const float4 u2 = *(const float4*)(t2 + k0);
        float kw[7];                           // (k0 + c - j0 - r), c:0..3, r:0..3
        #pragma unroll
        for (int i = 0; i < 7; ++i) {
            const int widx = (k0 - j0 - 3 + i) & MASK;
            kw[i] = skey[widx + (widx >> 5)];
        }
        #pragma unroll
        for (int r = 0; r < 4; ++r) {
            const float kv0 = kw[3 - r], kv1 = kw[4 - r], kv2 = kw[5 - r], kv3 = kw[6 - r];
            acc[r][0] += kv0 * xv.x + kv1 * xv.y + kv2 * xv.z + kv3 * xv.w;
            acc[r][1] += kv0 * u1.x + kv1 * u1.y + kv2 * u1.z + kv3 * u1.w;
            acc[r][2] += kv0 * u2.x + kv1 * u2.y + kv2 * u2.z + kv3 * u2.w;
        }
    }

    float rv[3];
    #pragma unroll
    for (int v = 0; v < 3; ++v)
        rv[v] = greduce4(acc[0][v], acc[1][v], acc[2][v], acc[3][v]);

    const int lane = t & 63, wave = t >> 6, sg = lane >> 4;
    const int off = (0x3120 >> (sg * 4)) & 0xF;  // which row this lane holds
    if ((lane & 15) == 0) {
        #pragma unroll
        for (int v = 0; v < 3; ++v) sred[wave * 12 + v * 4 + off] = rv[v];
    }
    __syncthreads();

    if (t < 4) {
        const int j = j0 + t;
        float vb = 0.f, v1 = 0.f, v2 = 0.f;
        #pragma unroll
        for (int wv = 0; wv < 4; ++wv) {
            vb += sred[wv * 12 + 0 + t];
            v1 += sred[wv * 12 + 4 + t];
            v2 += sred[wv * 12 + 8 + t];
        }
        const float dd1 = d1[j], dd2 = d2[j];
        const float r2 = v1 - dd1 * o1[j];
        const float r4 = v2 - dd2 * o2[j];
        out[j] = (vb - r2 - r4) / dd1;
        if (j == N - 1) out[N] = dd2;          // redun3 = d2[last row]
    }
}

extern "C" void kernel_launch(void* const* d_in, const int* in_sizes, int n_in,
                              void* d_out, int out_size, void* d_ws, size_t ws_size,
                              hipStream_t stream) {
    const float* key = (const float*)d_in[0];
    const float* x   = (const float*)d_in[1];
    const float* km1 = (const float*)d_in[2];
    const float* o1  = (const float*)d_in[3];
    const float* km2 = (const float*)d_in[4];
    const float* o2  = (const float*)d_in[5];
    float* out = (float*)d_out;

    float* ws = (float*)d_ws;
    float* tpart1 = ws;                                  // 256*4096
    float* tpart2 = tpart1 + (size_t)256 * N;            // 256*4096
    float* dpart1 = tpart2 + (size_t)256 * N;            // 4096*16
    float* dpart2 = dpart1 + (size_t)N * 16;             // 4096*16
    float* t1     = dpart2 + (size_t)N * 16;             // 4096
    float* t2     = t1 + N;
    float* d1     = t2 + N;
    float* d2     = d1 + N;

    hipLaunchKernelGGL(k1_fused, dim3(1024), dim3(256), 0, stream,
                       key, km1, km2, o1, o2, tpart1, tpart2, dpart1, dpart2);
    hipLaunchKernelGGL(k2_reduce, dim3(272), dim3(256), 0, stream,
                       tpart1, tpart2, dpart1, dpart2, t1, t2, d1, d2);
    hipLaunchKernelGGL(k3_final, dim3(1024), dim3(256), 0, stream,
                       key, x, t1, t2, d1, d2, o1, o2, out);
}

// Round 10
// 36.313 us; speedup vs baseline: 1.3942x; 1.0320x over previous
//
#include <hip/hip_runtime.h>

#define N 4096
#define MASK 4095

// 32-lane butterfly sum (within each 32-lane half of a wave64).
__device__ __forceinline__ float red32(float v) {
    v += __shfl_xor(v, 1, 64);
    v += __shfl_xor(v, 2, 64);
    v += __shfl_xor(v, 4, 64);
    v += __shfl_xor(v, 8, 64);
    v += __shfl_xor(v, 16, 64);
    return v;
}

// Merge-tree reduction used by K3 (4 independent 64-lane sums, 7 shuffles).
// Result mapping: lane-group sg = lane>>4: sg0->g0, sg1->g2, sg2->g1, sg3->g3.
__device__ __forceinline__ float fold(float u, float v, int m) {
    const bool hi = (threadIdx.x & m) != 0;
    const float t = hi ? u : v;
    const float s = __shfl_xor(t, m, 64);
    return (hi ? v : u) + s;
}

__device__ __forceinline__ float greduce4(float g0, float g1, float g2, float g3) {
    float c1 = fold(g0, g1, 32);
    float c2 = fold(g2, g3, 32);
    float e  = fold(c1, c2, 16);
    e += __shfl_xor(e, 8, 64);
    e += __shfl_xor(e, 4, 64);
    e += __shfl_xor(e, 2, 64);
    e += __shfl_xor(e, 1, 64);
    return e;
}

// ---------------------------------------------------------------------------
// K1: single pass, one matrix per block, 32 rows x 2048 cols per block
//   (256 KB retired/block). grid 512 x 256: mat = b>>8; sub = b&255;
//   rc = sub>>1 (32-row chunk), cs = sub&1 (2048-col stripe).
//   Thread t owns cols c0+8t..8t+7; rows processed in four 8-row register
//   groups (w[15] window + dpa[8] partials, ~60 VGPR -- the no-spill regime
//   proven in rounds 8/9). Hot loop = pure float4 loads + FMAs; red32
//   leaders write dpart[row][16] directly. tp[8] accumulates 32 rows ->
//   tpart slices halve vs round 9 (128/matrix, 4 MB total each way).
// ---------------------------------------------------------------------------
__global__ __launch_bounds__(256) void k1_fused(
    const float* __restrict__ key,
    const float* __restrict__ km1, const float* __restrict__ km2,
    const float* __restrict__ o1, const float* __restrict__ o2,
    float* __restrict__ tpart1, float* __restrict__ tpart2,
    float* __restrict__ dpart1, float* __restrict__ dpart2)
{
    __shared__ float skey[4096 + 128];
    const int t = threadIdx.x;
    const int b = blockIdx.x;
    const int mat = b >> 8;
    const int sub = b & 255;
    const int rc = sub >> 1;
    const int cs = sub & 1;
    const int j0 = rc * 32;
    const int c0 = cs * 2048;

    const float* __restrict__ km = mat ? km2 : km1;
    const float* __restrict__ o  = mat ? o2  : o1;
    float* __restrict__ tp_out   = mat ? tpart2 : tpart1;
    float* __restrict__ dp_out   = mat ? dpart2 : dpart1;

    #pragma unroll
    for (int q = 0; q < 4; ++q) {
        const float4 kv = ((const float4*)key)[q * 256 + t];
        const int idx = (q * 256 + t) * 4;
        skey[(idx + 0) + ((idx + 0) >> 5)] = kv.x;
        skey[(idx + 1) + ((idx + 1) >> 5)] = kv.y;
        skey[(idx + 2) + ((idx + 2) >> 5)] = kv.z;
        skey[(idx + 3) + ((idx + 3) >> 5)] = kv.w;
    }
    __syncthreads();

    const int col0 = c0 + 8 * t;
    const float4* qp = (const float4*)km + (size_t)j0 * 1024 + (c0 >> 2) + 2 * t;
    const int hw = t >> 5;               // half-wave index 0..7

    float tp[8];
    #pragma unroll
    for (int i = 0; i < 8; ++i) tp[i] = 0.f;

    for (int g = 0; g < 4; ++g) {
        const int jbase = j0 + 8 * g;
        const float4* qh = qp + (size_t)g * 8 * 1024;

        // key window for this group: w[i] = key[(col0 - jbase - 7 + i) & 4095]
        // row jbase+r, col col0+cx  ->  w[cx + 7 - r]
        float w[15];
        #pragma unroll
        for (int i = 0; i < 15; ++i) {
            const int idx = (col0 - jbase - 7 + i) & MASK;
            w[i] = skey[idx + (idx >> 5)];
        }

        float dpa[8];
        #pragma unroll
        for (int rb = 0; rb < 4; ++rb) {
            const int r0 = 2 * rb, r1 = 2 * rb + 1;
            const float4 a0 = qh[(size_t)r0 * 1024];
            const float4 b0 = qh[(size_t)r0 * 1024 + 1];
            const float4 a1 = qh[(size_t)r1 * 1024];
            const float4 b1 = qh[(size_t)r1 * 1024 + 1];
            const float oa0 = o[jbase + r0];
            const float oa1 = o[jbase + r1];

            tp[0] += oa0 * a0.x; tp[1] += oa0 * a0.y; tp[2] += oa0 * a0.z; tp[3] += oa0 * a0.w;
            tp[4] += oa0 * b0.x; tp[5] += oa0 * b0.y; tp[6] += oa0 * b0.z; tp[7] += oa0 * b0.w;
            dpa[r0] = w[7 - r0] * a0.x + w[8 - r0] * a0.y + w[9 - r0] * a0.z + w[10 - r0] * a0.w
                    + w[11 - r0] * b0.x + w[12 - r0] * b0.y + w[13 - r0] * b0.z + w[14 - r0] * b0.w;

            tp[0] += oa1 * a1.x; tp[1] += oa1 * a1.y; tp[2] += oa1 * a1.z; tp[3] += oa1 * a1.w;
            tp[4] += oa1 * b1.x; tp[5] += oa1 * b1.y; tp[6] += oa1 * b1.z; tp[7] += oa1 * b1.w;
            dpa[r1] = w[7 - r1] * a1.x + w[8 - r1] * a1.y + w[9 - r1] * a1.z + w[10 - r1] * a1.w
                    + w[11 - r1] * b1.x + w[12 - r1] * b1.y + w[13 - r1] * b1.z + w[14 - r1] * b1.w;
        }

        // per-group reduction: half-wave butterflies, leaders write dpart.
        #pragma unroll
        for (int r = 0; r < 8; ++r) {
            const float v = red32(dpa[r]);
            if ((t & 31) == 0)
                dp_out[(size_t)(jbase + r) * 16 + cs * 8 + hw] = v;
        }
    }

    // t-partials: 8 cols/thread = two float4 stores.
    float4* tpo = (float4*)(tp_out + (size_t)rc * N + c0) + 2 * t;
    tpo[0] = make_float4(tp[0], tp[1], tp[2], tp[3]);
    tpo[1] = make_float4(tp[4], tp[5], tp[6], tp[7]);
}

// ---------------------------------------------------------------------------
// K2: reduce partials. grid = 272 x 256.
//   blocks [0,256):    t-reduce over 128 slices (32 cols per block).
//   blocks [256,272):  d-reduce: 16 partials per row per thread.
// ---------------------------------------------------------------------------
__global__ __launch_bounds__(256) void k2_reduce(
    const float* __restrict__ tpart1, const float* __restrict__ tpart2,
    const float* __restrict__ dpart1, const float* __restrict__ dpart2,
    float* __restrict__ t1, float* __restrict__ t2,
    float* __restrict__ d1, float* __restrict__ d2)
{
    __shared__ float sdata[256];
    const int b = blockIdx.x;
    const int t = threadIdx.x;

    if (b < 256) {
        const float* src = (b < 128) ? tpart1 : tpart2;
        float* dst       = (b < 128) ? t1 : t2;
        const int colbase = (b & 127) * 32;
        const int col = t & 31;
        const int sg = t >> 5;
        float a0 = 0.f, a1 = 0.f, a2 = 0.f, a3 = 0.f;
        #pragma unroll 4
        for (int k = 0; k < 16; k += 4) {
            a0 += src[(size_t)(sg + 8 * (k + 0)) * N + colbase + col];
            a1 += src[(size_t)(sg + 8 * (k + 1)) * N + colbase + col];
            a2 += src[(size_t)(sg + 8 * (k + 2)) * N + colbase + col];
            a3 += src[(size_t)(sg + 8 * (k + 3)) * N + colbase + col];
        }
        sdata[t] = (a0 + a1) + (a2 + a3);
        __syncthreads();
        if (t < 32) {
            float s = 0.f;
            #pragma unroll
            for (int i = 0; i < 8; ++i) s += sdata[i * 32 + t];
            dst[colbase + t] = s;
        }
    } else {
        const int row = (b - 256) * 256 + t;
        const float4* p1 = (const float4*)(dpart1 + (size_t)row * 16);
        const float4* p2 = (const float4*)(dpart2 + (size_t)row * 16);
        float s1 = 0.f, s2 = 0.f;
        #pragma unroll
        for (int i = 0; i < 4; ++i) {
            const float4 v1 = p1[i];
            const float4 v2 = p2[i];
            s1 += (v1.x + v1.y) + (v1.z + v1.w);
            s2 += (v2.x + v2.y) + (v2.z + v2.w);
        }
        d1[row] = s1;
        d2[row] = s2;
    }
}

// ---------------------------------------------------------------------------
// K3: three circulant matvecs + final combine. 1024 blocks x 4 rows each.
// ---------------------------------------------------------------------------
__global__ __launch_bounds__(256) void k3_final(
    const float* __restrict__ key, const float* __restrict__ x,
    const float* __restrict__ t1, const float* __restrict__ t2,
    const float* __restrict__ d1, const float* __restrict__ d2,
    const float* __restrict__ o1, const float* __restrict__ o2,
    float* __restrict__ out)
{
    __shared__ float skey[4096 + 128];
    __shared__ float sred[48];                 // [wave][v][row]
    const int t = threadIdx.x;
    const int j0 = blockIdx.x * 4;

    #pragma unroll
    for (int q = 0; q < 16; ++q) {
        const int idx = q * 256 + t;
        skey[idx + (idx >> 5)] = key[idx];
    }
    __syncthreads();

    float acc[4][3];
    #pragma unroll
    for (int r = 0; r < 4; ++r)
        #pragma unroll
        for (int v = 0; v < 3; ++v) acc[r][v] = 0.f;

    #pragma unroll
    for (int q = 0; q < 4; ++q) {
        const int k0 = q * 1024 + 4 * t;
        const float4 xv = *(const float4*)(x + k0);
        const float4 u1 = *(const float4*)(t1 + k0);
        const float4 u2 = *(const float4*)(t2 + k0);
        float kw[7];                           // (k0 + c - j0 - r), c:0..3, r:0..3
        #pragma unroll
        for (int i = 0; i < 7; ++i) {
            const int widx = (k0 - j0 - 3 + i) & MASK;
            kw[i] = skey[widx + (widx >> 5)];
        }
        #pragma unroll
        for (int r = 0; r < 4; ++r) {
            const float kv0 = kw[3 - r], kv1 = kw[4 - r], kv2 = kw[5 - r], kv3 = kw[6 - r];
            acc[r][0] += kv0 * xv.x + kv1 * xv.y + kv2 * xv.z + kv3 * xv.w;
            acc[r][1] += kv0 * u1.x + kv1 * u1.y + kv2 * u1.z + kv3 * u1.w;
            acc[r][2] += kv0 * u2.x + kv1 * u2.y + kv2 * u2.z + kv3 * u2.w;
        }
    }

    float rv[3];
    #pragma unroll
    for (int v = 0; v < 3; ++v)
        rv[v] = greduce4(acc[0][v], acc[1][v], acc[2][v], acc[3][v]);

    const int lane = t & 63, wave = t >> 6, sg = lane >> 4;
    const int off = (0x3120 >> (sg * 4)) & 0xF;  // which row this lane holds
    if ((lane & 15) == 0) {
        #pragma unroll
        for (int v = 0; v < 3; ++v) sred[wave * 12 + v * 4 + off] = rv[v];
    }
    __syncthreads();

    if (t < 4) {
        const int j = j0 + t;
        float vb = 0.f, v1 = 0.f, v2 = 0.f;
        #pragma unroll
        for (int wv = 0; wv < 4; ++wv) {
            vb += sred[wv * 12 + 0 + t];
            v1 += sred[wv * 12 + 4 + t];
            v2 += sred[wv * 12 + 8 + t];
        }
        const float dd1 = d1[j], dd2 = d2[j];
        const float r2 = v1 - dd1 * o1[j];
        const float r4 = v2 - dd2 * o2[j];
        out[j] = (vb - r2 - r4) / dd1;
        if (j == N - 1) out[N] = dd2;          // redun3 = d2[last row]
    }
}

extern "C" void kernel_launch(void* const* d_in, const int* in_sizes, int n_in,
                              void* d_out, int out_size, void* d_ws, size_t ws_size,
                              hipStream_t stream) {
    const float* key = (const float*)d_in[0];
    const float* x   = (const float*)d_in[1];
    const float* km1 = (const float*)d_in[2];
    const float* o1  = (const float*)d_in[3];
    const float* km2 = (const float*)d_in[4];
    const float* o2  = (const float*)d_in[5];
    float* out = (float*)d_out;

    float* ws = (float*)d_ws;
    float* tpart1 = ws;                                  // 128*4096
    float* tpart2 = tpart1 + (size_t)128 * N;            // 128*4096
    float* dpart1 = tpart2 + (size_t)128 * N;            // 4096*16
    float* dpart2 = dpart1 + (size_t)N * 16;             // 4096*16
    float* t1     = dpart2 + (size_t)N * 16;             // 4096
    float* t2     = t1 + N;
    float* d1     = t2 + N;
    float* d2     = d1 + N;

    hipLaunchKernelGGL(k1_fused, dim3(512), dim3(256), 0, stream,
                       key, km1, km2, o1, o2, tpart1, tpart2, dpart1, dpart2);
    hipLaunchKernelGGL(k2_reduce, dim3(272), dim3(256), 0, stream,
                       tpart1, tpart2, dpart1, dpart2, t1, t2, d1, d2);
    hipLaunchKernelGGL(k3_final, dim3(1024), dim3(256), 0, stream,
                       key, x, t1, t2, d1, d2, o1, o2, out);
}

// Round 11
// 36.114 us; speedup vs baseline: 1.4019x; 1.0055x over previous
//
#include <hip/hip_runtime.h>

#define N 4096
#define MASK 4095

// 32-lane butterfly sum (within each 32-lane half of a wave64).
__device__ __forceinline__ float red32(float v) {
    v += __shfl_xor(v, 1, 64);
    v += __shfl_xor(v, 2, 64);
    v += __shfl_xor(v, 4, 64);
    v += __shfl_xor(v, 8, 64);
    v += __shfl_xor(v, 16, 64);
    return v;
}

// Merge-tree reduction (4 independent 64-lane sums, 7 shuffles).
// Result mapping: lane-group sg = lane>>4: sg0->g0, sg1->g2, sg2->g1, sg3->g3.
__device__ __forceinline__ float fold(float u, float v, int m) {
    const bool hi = (threadIdx.x & m) != 0;
    const float t = hi ? u : v;
    const float s = __shfl_xor(t, m, 64);
    return (hi ? v : u) + s;
}

__device__ __forceinline__ float greduce4(float g0, float g1, float g2, float g3) {
    float c1 = fold(g0, g1, 32);
    float c2 = fold(g2, g3, 32);
    float e  = fold(c1, c2, 16);
    e += __shfl_xor(e, 8, 64);
    e += __shfl_xor(e, 4, 64);
    e += __shfl_xor(e, 2, 64);
    e += __shfl_xor(e, 1, 64);
    return e;
}

// ---------------------------------------------------------------------------
// K1: single pass, one matrix per block, 32 rows x 2048 cols per block.
//   UNCHANGED from round 10 -- 9 structural variants (occupancy 9-57%, ILP
//   2-16 loads, aux traffic 35->4.7 MB) all land at ~43-47 us profiled:
//   the mandatory 128 MB stream runs at the chip's streaming read ceiling
//   (~4.3 TB/s effective). Do not restructure further.
// ---------------------------------------------------------------------------
__global__ __launch_bounds__(256) void k1_fused(
    const float* __restrict__ key,
    const float* __restrict__ km1, const float* __restrict__ km2,
    const float* __restrict__ o1, const float* __restrict__ o2,
    float* __restrict__ tpart1, float* __restrict__ tpart2,
    float* __restrict__ dpart1, float* __restrict__ dpart2)
{
    __shared__ float skey[4096 + 128];
    const int t = threadIdx.x;
    const int b = blockIdx.x;
    const int mat = b >> 8;
    const int sub = b & 255;
    const int rc = sub >> 1;
    const int cs = sub & 1;
    const int j0 = rc * 32;
    const int c0 = cs * 2048;

    const float* __restrict__ km = mat ? km2 : km1;
    const float* __restrict__ o  = mat ? o2  : o1;
    float* __restrict__ tp_out   = mat ? tpart2 : tpart1;
    float* __restrict__ dp_out   = mat ? dpart2 : dpart1;

    #pragma unroll
    for (int q = 0; q < 4; ++q) {
        const float4 kv = ((const float4*)key)[q * 256 + t];
        const int idx = (q * 256 + t) * 4;
        skey[(idx + 0) + ((idx + 0) >> 5)] = kv.x;
        skey[(idx + 1) + ((idx + 1) >> 5)] = kv.y;
        skey[(idx + 2) + ((idx + 2) >> 5)] = kv.z;
        skey[(idx + 3) + ((idx + 3) >> 5)] = kv.w;
    }
    __syncthreads();

    const int col0 = c0 + 8 * t;
    const float4* qp = (const float4*)km + (size_t)j0 * 1024 + (c0 >> 2) + 2 * t;
    const int hw = t >> 5;               // half-wave index 0..7

    float tp[8];
    #pragma unroll
    for (int i = 0; i < 8; ++i) tp[i] = 0.f;

    for (int g = 0; g < 4; ++g) {
        const int jbase = j0 + 8 * g;
        const float4* qh = qp + (size_t)g * 8 * 1024;

        float w[15];
        #pragma unroll
        for (int i = 0; i < 15; ++i) {
            const int idx = (col0 - jbase - 7 + i) & MASK;
            w[i] = skey[idx + (idx >> 5)];
        }

        float dpa[8];
        #pragma unroll
        for (int rb = 0; rb < 4; ++rb) {
            const int r0 = 2 * rb, r1 = 2 * rb + 1;
            const float4 a0 = qh[(size_t)r0 * 1024];
            const float4 b0 = qh[(size_t)r0 * 1024 + 1];
            const float4 a1 = qh[(size_t)r1 * 1024];
            const float4 b1 = qh[(size_t)r1 * 1024 + 1];
            const float oa0 = o[jbase + r0];
            const float oa1 = o[jbase + r1];

            tp[0] += oa0 * a0.x; tp[1] += oa0 * a0.y; tp[2] += oa0 * a0.z; tp[3] += oa0 * a0.w;
            tp[4] += oa0 * b0.x; tp[5] += oa0 * b0.y; tp[6] += oa0 * b0.z; tp[7] += oa0 * b0.w;
            dpa[r0] = w[7 - r0] * a0.x + w[8 - r0] * a0.y + w[9 - r0] * a0.z + w[10 - r0] * a0.w
                    + w[11 - r0] * b0.x + w[12 - r0] * b0.y + w[13 - r0] * b0.z + w[14 - r0] * b0.w;

            tp[0] += oa1 * a1.x; tp[1] += oa1 * a1.y; tp[2] += oa1 * a1.z; tp[3] += oa1 * a1.w;
            tp[4] += oa1 * b1.x; tp[5] += oa1 * b1.y; tp[6] += oa1 * b1.z; tp[7] += oa1 * b1.w;
            dpa[r1] = w[7 - r1] * a1.x + w[8 - r1] * a1.y + w[9 - r1] * a1.z + w[10 - r1] * a1.w
                    + w[11 - r1] * b1.x + w[12 - r1] * b1.y + w[13 - r1] * b1.z + w[14 - r1] * b1.w;
        }

        #pragma unroll
        for (int r = 0; r < 8; ++r) {
            const float v = red32(dpa[r]);
            if ((t & 31) == 0)
                dp_out[(size_t)(jbase + r) * 16 + cs * 8 + hw] = v;
        }
    }

    float4* tpo = (float4*)(tp_out + (size_t)rc * N + c0) + 2 * t;
    tpo[0] = make_float4(tp[0], tp[1], tp[2], tp[3]);
    tpo[1] = make_float4(tp[4], tp[5], tp[6], tp[7]);
}

// ---------------------------------------------------------------------------
// K2: reduce partials. grid = 272 x 256. (unchanged from round 10)
// ---------------------------------------------------------------------------
__global__ __launch_bounds__(256) void k2_reduce(
    const float* __restrict__ tpart1, const float* __restrict__ tpart2,
    const float* __restrict__ dpart1, const float* __restrict__ dpart2,
    float* __restrict__ t1, float* __restrict__ t2,
    float* __restrict__ d1, float* __restrict__ d2)
{
    __shared__ float sdata[256];
    const int b = blockIdx.x;
    const int t = threadIdx.x;

    if (b < 256) {
        const float* src = (b < 128) ? tpart1 : tpart2;
        float* dst       = (b < 128) ? t1 : t2;
        const int colbase = (b & 127) * 32;
        const int col = t & 31;
        const int sg = t >> 5;
        float a0 = 0.f, a1 = 0.f, a2 = 0.f, a3 = 0.f;
        #pragma unroll 4
        for (int k = 0; k < 16; k += 4) {
            a0 += src[(size_t)(sg + 8 * (k + 0)) * N + colbase + col];
            a1 += src[(size_t)(sg + 8 * (k + 1)) * N + colbase + col];
            a2 += src[(size_t)(sg + 8 * (k + 2)) * N + colbase + col];
            a3 += src[(size_t)(sg + 8 * (k + 3)) * N + colbase + col];
        }
        sdata[t] = (a0 + a1) + (a2 + a3);
        __syncthreads();
        if (t < 32) {
            float s = 0.f;
            #pragma unroll
            for (int i = 0; i < 8; ++i) s += sdata[i * 32 + t];
            dst[colbase + t] = s;
        }
    } else {
        const int row = (b - 256) * 256 + t;
        const float4* p1 = (const float4*)(dpart1 + (size_t)row * 16);
        const float4* p2 = (const float4*)(dpart2 + (size_t)row * 16);
        float s1 = 0.f, s2 = 0.f;
        #pragma unroll
        for (int i = 0; i < 4; ++i) {
            const float4 v1 = p1[i];
            const float4 v2 = p2[i];
            s1 += (v1.x + v1.y) + (v1.z + v1.w);
            s2 += (v2.x + v2.y) + (v2.z + v2.w);
        }
        d1[row] = s1;
        d2[row] = s2;
    }
}

// ---------------------------------------------------------------------------
// K3: three circulant matvecs + final combine. 512 blocks x 8 rows each
//   (was 1024 x 4 with 16 SCALAR key loads/thread). Key staged via float4
//   (4 insts/thread); acc[8][3] + kw[11] ~ 60 VGPR (no-spill regime).
//   Staging traffic 16 MB -> 8 MB, staging instruction count / 8.
// ---------------------------------------------------------------------------
__global__ __launch_bounds__(256) void k3_final(
    const float* __restrict__ key, const float* __restrict__ x,
    const float* __restrict__ t1, const float* __restrict__ t2,
    const float* __restrict__ d1, const float* __restrict__ d2,
    const float* __restrict__ o1, const float* __restrict__ o2,
    float* __restrict__ out)
{
    __shared__ float skey[4096 + 128];
    __shared__ float sred[4][3][8];            // [wave][comp][row]
    const int t = threadIdx.x;
    const int j0 = blockIdx.x * 8;

    #pragma unroll
    for (int q = 0; q < 4; ++q) {
        const float4 kv = ((const float4*)key)[q * 256 + t];
        const int idx = (q * 256 + t) * 4;
        skey[(idx + 0) + ((idx + 0) >> 5)] = kv.x;
        skey[(idx + 1) + ((idx + 1) >> 5)] = kv.y;
        skey[(idx + 2) + ((idx + 2) >> 5)] = kv.z;
        skey[(idx + 3) + ((idx + 3) >> 5)] = kv.w;
    }
    __syncthreads();

    float acc[8][3];
    #pragma unroll
    for (int r = 0; r < 8; ++r)
        #pragma unroll
        for (int v = 0; v < 3; ++v) acc[r][v] = 0.f;

    #pragma unroll
    for (int q = 0; q < 4; ++q) {
        const int k0 = q * 1024 + 4 * t;
        const float4 xv = *(const float4*)(x + k0);
        const float4 u1 = *(const float4*)(t1 + k0);
        const float4 u2 = *(const float4*)(t2 + k0);
        float kw[11];                          // (k0 + c - j0 - r), c:0..3, r:0..7
        #pragma unroll
        for (int i = 0; i < 11; ++i) {
            const int widx = (k0 - j0 - 7 + i) & MASK;
            kw[i] = skey[widx + (widx >> 5)];
        }
        #pragma unroll
        for (int r = 0; r < 8; ++r) {
            const float kv0 = kw[7 - r], kv1 = kw[8 - r], kv2 = kw[9 - r], kv3 = kw[10 - r];
            acc[r][0] += kv0 * xv.x + kv1 * xv.y + kv2 * xv.z + kv3 * xv.w;
            acc[r][1] += kv0 * u1.x + kv1 * u1.y + kv2 * u1.z + kv3 * u1.w;
            acc[r][2] += kv0 * u2.x + kv1 * u2.y + kv2 * u2.z + kv3 * u2.w;
        }
    }

    const int lane = t & 63, wave = t >> 6, sg = lane >> 4;
    const int off = (0x3120 >> (sg * 4)) & 0xF;  // which row this lane holds
    #pragma unroll
    for (int hf = 0; hf < 2; ++hf) {
        #pragma unroll
        for (int v = 0; v < 3; ++v) {
            const float e = greduce4(acc[4 * hf + 0][v], acc[4 * hf + 1][v],
                                     acc[4 * hf + 2][v], acc[4 * hf + 3][v]);
            if ((lane & 15) == 0) sred[wave][v][hf * 4 + off] = e;
        }
    }
    __syncthreads();

    if (t < 8) {
        const int j = j0 + t;
        const float vb = sred[0][0][t] + sred[1][0][t] + sred[2][0][t] + sred[3][0][t];
        const float v1 = sred[0][1][t] + sred[1][1][t] + sred[2][1][t] + sred[3][1][t];
        const float v2 = sred[0][2][t] + sred[1][2][t] + sred[2][2][t] + sred[3][2][t];
        const float dd1 = d1[j], dd2 = d2[j];
        const float r2 = v1 - dd1 * o1[j];
        const float r4 = v2 - dd2 * o2[j];
        out[j] = (vb - r2 - r4) / dd1;
        if (j == N - 1) out[N] = dd2;          // redun3 = d2[last row]
    }
}

extern "C" void kernel_launch(void* const* d_in, const int* in_sizes, int n_in,
                              void* d_out, int out_size, void* d_ws, size_t ws_size,
                              hipStream_t stream) {
    const float* key = (const float*)d_in[0];
    const float* x   = (const float*)d_in[1];
    const float* km1 = (const float*)d_in[2];
    const float* o1  = (const float*)d_in[3];
    const float* km2 = (const float*)d_in[4];
    const float* o2  = (const float*)d_in[5];
    float* out = (float*)d_out;

    float* ws = (float*)d_ws;
    float* tpart1 = ws;                                  // 128*4096
    float* tpart2 = tpart1 + (size_t)128 * N;            // 128*4096
    float* dpart1 = tpart2 + (size_t)128 * N;            // 4096*16
    float* dpart2 = dpart1 + (size_t)N * 16;             // 4096*16
    float* t1     = dpart2 + (size_t)N * 16;             // 4096
    float* t2     = t1 + N;
    float* d1     = t2 + N;
    float* d2     = d1 + N;

    hipLaunchKernelGGL(k1_fused, dim3(512), dim3(256), 0, stream,
                       key, km1, km2, o1, o2, tpart1, tpart2, dpart1, dpart2);
    hipLaunchKernelGGL(k2_reduce, dim3(272), dim3(256), 0, stream,
                       tpart1, tpart2, dpart1, dpart2, t1, t2, d1, d2);
    hipLaunchKernelGGL(k3_final, dim3(512), dim3(256), 0, stream,
                       key, x, t1, t2, d1, d2, o1, o2, out);
}